// Round 1
// baseline (3157.466 us; speedup 1.0000x reference)
//
#include <hip/hip_runtime.h>

// HGNN: 3 layers of e = act(A @ (A^T @ e)) over sparse adj (N=150000, E=4.8M, D=64).
// Strategy: build CSR (rows) + CSC (cols) per launch, then pull-based SpMM
// (wave per row, lane per feature column), fusing LeakyReLU / LayerNorm+residual
// into the SpMM epilogues.

#define NTOT 150000
#define NE   4800000
#define DD   64

// ---------------- build: histogram ----------------
__global__ __launch_bounds__(256) void k_count(const int* __restrict__ rows,
                                               const int* __restrict__ cols,
                                               int* __restrict__ cnt_r,
                                               int* __restrict__ cnt_c) {
    int e = blockIdx.x * 256 + threadIdx.x;
    if (e < NE) {
        atomicAdd(&cnt_r[rows[e]], 1);
        atomicAdd(&cnt_c[cols[e]], 1);
    }
}

// ---------------- build: single-block exclusive scan ----------------
// 1024 threads, chunked; writes exclusive scan to starts[] and cur[], starts[n]=total.
__global__ __launch_bounds__(1024) void k_scan(const int* __restrict__ cnt,
                                               int* __restrict__ starts,
                                               int* __restrict__ cur, int n) {
    __shared__ int wtot[16];
    __shared__ int wexcl[16];
    __shared__ int ctot;
    const int tid  = threadIdx.x;
    const int lane = tid & 63;
    const int wv   = tid >> 6;
    int carry = 0;
    for (int base = 0; base < n; base += 1024) {
        int i = base + tid;
        int v = (i < n) ? cnt[i] : 0;
        int s = v;
        #pragma unroll
        for (int off = 1; off < 64; off <<= 1) {
            int t = __shfl_up(s, off);
            if (lane >= off) s += t;
        }
        if (lane == 63) wtot[wv] = s;
        __syncthreads();
        if (tid == 0) {
            int run = 0;
            #pragma unroll
            for (int w2 = 0; w2 < 16; ++w2) { wexcl[w2] = run; run += wtot[w2]; }
            ctot = run;
        }
        __syncthreads();
        int excl = carry + wexcl[wv] + (s - v);
        if (i < n) { starts[i] = excl; cur[i] = excl; }
        carry += ctot;
        __syncthreads();   // protect wtot/wexcl/ctot before next chunk
    }
    if (tid == 0) starts[n] = carry;
}

// ---------------- build: scatter edges into CSR + CSC ----------------
__global__ __launch_bounds__(256) void k_scatter(const int* __restrict__ rows,
                                                 const int* __restrict__ cols,
                                                 const float* __restrict__ vals,
                                                 int* __restrict__ cur_r,
                                                 int* __restrict__ cur_c,
                                                 int2* __restrict__ csr,
                                                 int2* __restrict__ csc) {
    int e = blockIdx.x * 256 + threadIdx.x;
    if (e >= NE) return;
    int r = rows[e], c = cols[e];
    int vb = __float_as_int(vals[e]);
    int p = atomicAdd(&cur_r[r], 1);
    int2 er; er.x = c; er.y = vb;
    csr[p] = er;
    int q = atomicAdd(&cur_c[c], 1);
    int2 ec; ec.x = r; ec.y = vb;
    csc[q] = ec;
}

// ---------------- pull SpMM: y[r] = sum val * x[idx], wave per row ----------------
// MODE 0: plain store; MODE 1: LeakyReLU(0.5); MODE 2: LayerNorm*gamma+beta + ego residual
template <int MODE>
__global__ __launch_bounds__(256) void k_spmm(const int* __restrict__ starts,
                                              const int2* __restrict__ edges,
                                              const float* __restrict__ x,
                                              float* __restrict__ y,
                                              const float* __restrict__ gamma,
                                              const float* __restrict__ beta,
                                              const float* __restrict__ ego) {
    int gid  = blockIdx.x * 256 + threadIdx.x;
    int wid  = gid >> 6;         // row
    int lane = threadIdx.x & 63; // feature column
    if (wid >= NTOT) return;
    int s  = starts[wid];
    int e2 = starts[wid + 1];
    float acc = 0.f;
    for (int base = s; base < e2; base += 64) {
        int idx = base + lane;
        int2 ed;
        if (idx < e2) ed = edges[idx];
        else { ed.x = 0; ed.y = 0; }
        int cnt = e2 - base; if (cnt > 64) cnt = 64;
        #pragma unroll 4
        for (int j = 0; j < cnt; ++j) {
            int   c = __shfl(ed.x, j);
            float v = __int_as_float(__shfl(ed.y, j));
            acc = fmaf(v, x[c * DD + lane], acc);
        }
    }
    if (MODE == 0) {
        y[wid * DD + lane] = acc;
    } else if (MODE == 1) {
        y[wid * DD + lane] = acc > 0.f ? acc : 0.5f * acc;
    } else {
        float sum = acc;
        #pragma unroll
        for (int off = 32; off; off >>= 1) sum += __shfl_xor(sum, off);
        float mu = sum * (1.f / 64.f);
        float d  = acc - mu;
        float vs = d * d;
        #pragma unroll
        for (int off = 32; off; off >>= 1) vs += __shfl_xor(vs, off);
        float var = vs * (1.f / 64.f);
        float rs  = rsqrtf(var + 1e-5f);
        y[wid * DD + lane] = d * rs * gamma[lane] + beta[lane] + ego[wid * DD + lane];
    }
}

// ---------------- fallback: atomic push SpMM (wave per edge) ----------------
__global__ __launch_bounds__(256) void k_push(const int* __restrict__ src_idx,
                                              const int* __restrict__ dst_idx,
                                              const float* __restrict__ vals,
                                              const float* __restrict__ x,
                                              float* __restrict__ y) {
    int gid  = blockIdx.x * 256 + threadIdx.x;
    int e    = gid >> 6;
    int lane = gid & 63;
    if (e >= NE) return;
    int s = src_idx[e], d = dst_idx[e];
    float v = vals[e];
    atomicAdd(&y[d * DD + lane], v * x[s * DD + lane]);
}

__global__ __launch_bounds__(256) void k_leaky(float* __restrict__ x, int n) {
    int i = blockIdx.x * 256 + threadIdx.x;
    if (i < n) { float v = x[i]; x[i] = v > 0.f ? v : 0.5f * v; }
}

__global__ __launch_bounds__(256) void k_ln(const float* __restrict__ z,
                                            const float* __restrict__ gamma,
                                            const float* __restrict__ beta,
                                            const float* __restrict__ ego,
                                            float* __restrict__ out) {
    int gid  = blockIdx.x * 256 + threadIdx.x;
    int wid  = gid >> 6;
    int lane = threadIdx.x & 63;
    if (wid >= NTOT) return;
    float v = z[wid * DD + lane];
    float sum = v;
    #pragma unroll
    for (int off = 32; off; off >>= 1) sum += __shfl_xor(sum, off);
    float mu = sum * (1.f / 64.f);
    float d  = v - mu;
    float vs = d * d;
    #pragma unroll
    for (int off = 32; off; off >>= 1) vs += __shfl_xor(vs, off);
    float var = vs * (1.f / 64.f);
    float rs  = rsqrtf(var + 1e-5f);
    out[wid * DD + lane] = d * rs * gamma[lane] + beta[lane] + ego[wid * DD + lane];
}

extern "C" void kernel_launch(void* const* d_in, const int* in_sizes, int n_in,
                              void* d_out, int out_size, void* d_ws, size_t ws_size,
                              hipStream_t stream) {
    const float* ego   = (const float*)d_in[0];
    const float* vals  = (const float*)d_in[1];
    const float* gamma = (const float*)d_in[2];
    const float* beta  = (const float*)d_in[3];
    const int*   rows  = (const int*)d_in[4];
    const int*   cols  = (const int*)d_in[5];
    float* out = (float*)d_out;

    const size_t EDGE_BYTES = (size_t)NE * 8;        // 38,400,000
    const size_t META       = 600064;                // (N+1)*4 padded
    const size_t FEAT_BYTES = (size_t)NTOT * DD * 4; // 38,400,000
    const size_t NEED = 2 * EDGE_BYTES + 6 * META + FEAT_BYTES; // 118,800,384

    const int GRID_E = (NE + 255) / 256;       // 18750
    const int GRID_N = (NTOT * DD) / 256;      // 37500  (150000*64 % 256 == 0)

    if (ws_size >= NEED) {
        char* w = (char*)d_ws;
        int2* csr   = (int2*)(w);
        int2* csc   = (int2*)(w + EDGE_BYTES);
        int*  rs    = (int*)(w + 2 * EDGE_BYTES);
        int*  rsT   = (int*)(w + 2 * EDGE_BYTES + 1 * META);
        int*  cur_r = (int*)(w + 2 * EDGE_BYTES + 2 * META);
        int*  cur_c = (int*)(w + 2 * EDGE_BYTES + 3 * META);
        int*  cnt_r = (int*)(w + 2 * EDGE_BYTES + 4 * META);
        int*  cnt_c = (int*)(w + 2 * EDGE_BYTES + 5 * META);
        float* B1   = (float*)(w + 2 * EDGE_BYTES + 6 * META);

        hipMemsetAsync(cnt_r, 0, 2 * META, stream);  // cnt_r + cnt_c adjacent
        k_count<<<GRID_E, 256, 0, stream>>>(rows, cols, cnt_r, cnt_c);
        k_scan<<<1, 1024, 0, stream>>>(cnt_r, rs,  cur_r, NTOT);
        k_scan<<<1, 1024, 0, stream>>>(cnt_c, rsT, cur_c, NTOT);
        k_scatter<<<GRID_E, 256, 0, stream>>>(rows, cols, vals, cur_r, cur_c, csr, csc);

        // layer 0
        k_spmm<0><<<GRID_N, 256, 0, stream>>>(rsT, csc, ego, B1, nullptr, nullptr, nullptr);
        k_spmm<1><<<GRID_N, 256, 0, stream>>>(rs,  csr, B1,  out, nullptr, nullptr, nullptr);
        // layer 1
        k_spmm<0><<<GRID_N, 256, 0, stream>>>(rsT, csc, out, B1, nullptr, nullptr, nullptr);
        k_spmm<1><<<GRID_N, 256, 0, stream>>>(rs,  csr, B1,  out, nullptr, nullptr, nullptr);
        // layer 2 (fused LN + residual)
        k_spmm<0><<<GRID_N, 256, 0, stream>>>(rsT, csc, out, B1, nullptr, nullptr, nullptr);
        k_spmm<2><<<GRID_N, 256, 0, stream>>>(rs,  csr, B1,  out, gamma, beta, ego);
    } else {
        // atomic-push fallback: needs only one feature temp in ws; d_out is buffer 2
        float* B1 = (float*)d_ws;
        float* B2 = out;
        const int GRID_P = NE / 4;  // wave per edge, 4 waves/block
        const float* e = ego;
        for (int layer = 0; layer < 3; ++layer) {
            hipMemsetAsync(B1, 0, FEAT_BYTES, stream);
            k_push<<<GRID_P, 256, 0, stream>>>(rows, cols, vals, e, B1);   // t = A^T e
            hipMemsetAsync(B2, 0, FEAT_BYTES, stream);
            k_push<<<GRID_P, 256, 0, stream>>>(cols, rows, vals, B1, B2);  // z = A t
            if (layer < 2) {
                k_leaky<<<GRID_N, 256, 0, stream>>>(B2, NTOT * DD);
                e = B2;
            } else {
                k_ln<<<GRID_N, 256, 0, stream>>>(B2, gamma, beta, ego, out);
            }
        }
    }
}

// Round 2
// 2354.188 us; speedup vs baseline: 1.3412x; 1.3412x over previous
//
#include <hip/hip_runtime.h>
#include <hip/hip_fp16.h>

// HGNN: 3 layers of e = act(A @ (A^T @ e)), N=150000, E=4.8M, D=64.
// Build: bucket-binned counting sort (write-locality; kills 8x write amp of
// naive scatter). SpMM: pull, wave/row, fp16 features, 2 edges per iteration.

#define NTOT 150000
#define NE   4800000
#define DD   64
#define NB   147            // buckets of 1024 rows: ceil(150000/1024)
#define NB8  (NB * 8)       // per-(bucket, blockgroup) counters; group = blockIdx&7 ~ XCD
#define EPB  4688           // edges per build block: ceil(NE/1024)

// ---------- phase 1: per-group bucket histogram ----------
__global__ __launch_bounds__(256) void k_hist(const int* __restrict__ rows,
                                              const int* __restrict__ cols,
                                              int* __restrict__ ghR,
                                              int* __restrict__ ghC) {
    __shared__ int hR[NB], hC[NB];
    const int tid = threadIdx.x, bid = blockIdx.x, g = bid & 7;
    if (tid < NB) { hR[tid] = 0; hC[tid] = 0; }
    __syncthreads();
    const int e0 = bid * EPB;
    const int e1 = min(NE, e0 + EPB);
    for (int e = e0 + tid; e < e1; e += 256) {
        atomicAdd(&hR[rows[e] >> 10], 1);
        atomicAdd(&hC[cols[e] >> 10], 1);
    }
    __syncthreads();
    if (tid < NB) {
        if (hR[tid]) atomicAdd(&ghR[tid * 8 + g], hR[tid]);
        if (hC[tid]) atomicAdd(&ghC[tid * 8 + g], hC[tid]);
    }
}

// ---------- phase 2: scan (b,g) histograms -> segment bases + cursors ----------
__global__ __launch_bounds__(1024) void k_bases(const int* __restrict__ ghR,
                                                const int* __restrict__ ghC,
                                                int* __restrict__ baseR, int* __restrict__ curR,
                                                int* __restrict__ baseC, int* __restrict__ curC,
                                                int* __restrict__ startsR, int* __restrict__ startsC) {
    __shared__ int a[NB8];
    const int tid = threadIdx.x;
    for (int i = tid; i < NB8; i += 1024) a[i] = ghR[i];
    __syncthreads();
    if (tid == 0) { int run = 0; for (int i = 0; i < NB8; ++i) { int t = a[i]; a[i] = run; run += t; } }
    __syncthreads();
    for (int i = tid; i < NB8; i += 1024) { baseR[i] = a[i]; curR[i] = a[i]; }
    __syncthreads();
    for (int i = tid; i < NB8; i += 1024) a[i] = ghC[i];
    __syncthreads();
    if (tid == 0) {
        int run = 0; for (int i = 0; i < NB8; ++i) { int t = a[i]; a[i] = run; run += t; }
        startsR[NTOT] = NE; startsC[NTOT] = NE;
    }
    __syncthreads();
    for (int i = tid; i < NB8; i += 1024) { baseC[i] = a[i]; curC[i] = a[i]; }
}

// ---------- phase 3: bin edges into [bucket][group] segments ----------
// payload: x = (local_idx<<18) | other_idx  (local<1024: 10b, other<150000: 18b), y = val bits
__global__ __launch_bounds__(256) void k_bin(const int* __restrict__ rows,
                                             const int* __restrict__ cols,
                                             const float* __restrict__ vals,
                                             int* __restrict__ curR, int* __restrict__ curC,
                                             int2* __restrict__ binR, int2* __restrict__ binC) {
    const int tid = threadIdx.x, bid = blockIdx.x, g = bid & 7;
    const int e0 = bid * EPB;
    const int e1 = min(NE, e0 + EPB);
    for (int e = e0 + tid; e < e1; e += 256) {
        const int r = rows[e], c = cols[e];
        const int vb = __float_as_int(vals[e]);
        int2 pr; pr.x = ((r & 1023) << 18) | c; pr.y = vb;
        int p = atomicAdd(&curR[(r >> 10) * 8 + g], 1);
        binR[p] = pr;
        int2 pc; pc.x = ((c & 1023) << 18) | r; pc.y = vb;
        int q = atomicAdd(&curC[(c >> 10) * 8 + g], 1);
        binC[q] = pc;
    }
}

// ---------- phase 4: per-bucket LDS counting sort -> final CSR/CSC + starts ----------
__global__ __launch_bounds__(1024) void k_sort(const int* __restrict__ baseR,
                                               const int2* __restrict__ binR,
                                               int2* __restrict__ csr, int* __restrict__ startsR,
                                               const int* __restrict__ baseC,
                                               const int2* __restrict__ binC,
                                               int2* __restrict__ csc, int* __restrict__ startsC) {
    __shared__ int hist[1024];
    __shared__ int cur[1024];
    __shared__ int wtot[16], wexcl[16];
    const int tid = threadIdx.x;
    const int lane = tid & 63, wv = tid >> 6;
    const int dir = (blockIdx.x >= NB) ? 1 : 0;
    const int b = blockIdx.x - dir * NB;
    const int*  base   = dir ? baseC   : baseR;
    const int2* bin    = dir ? binC    : binR;
    int2*       out    = dir ? csc     : csr;
    int*        starts = dir ? startsC : startsR;
    const int ebase = base[b * 8];
    const int eend  = (b == NB - 1) ? NE : base[(b + 1) * 8];
    hist[tid] = 0;
    __syncthreads();
    for (int i = ebase + tid; i < eend; i += 1024)
        atomicAdd(&hist[((unsigned)bin[i].x) >> 18], 1);
    __syncthreads();
    const int v = hist[tid];
    int s = v;
    #pragma unroll
    for (int off = 1; off < 64; off <<= 1) { int t = __shfl_up(s, off); if (lane >= off) s += t; }
    if (lane == 63) wtot[wv] = s;
    __syncthreads();
    if (tid == 0) { int run = 0; for (int w = 0; w < 16; ++w) { wexcl[w] = run; run += wtot[w]; } }
    __syncthreads();
    const int excl = ebase + wexcl[wv] + (s - v);   // exclusive start for local row tid
    const int r0 = b << 10;
    if (r0 + tid < NTOT) starts[r0 + tid] = excl;
    cur[tid] = excl;
    __syncthreads();
    for (int i = ebase + tid; i < eend; i += 1024) {
        const int2 ed = bin[i];
        const int lr = ((unsigned)ed.x) >> 18;
        const int pos = atomicAdd(&cur[lr], 1);
        int2 o; o.x = ed.x & 0x3FFFF; o.y = ed.y;
        out[pos] = o;   // random within this bucket's ~262KB region: one block, one L2
    }
}

// ---------- ego fp32 -> fp16 ----------
__global__ __launch_bounds__(256) void k_cvt(const float2* __restrict__ x,
                                             __half2* __restrict__ y, int n2) {
    int i = blockIdx.x * 256 + threadIdx.x;
    if (i < n2) y[i] = __float22half2_rn(x[i]);
}

// ---------- pull SpMM, fp16 features, 2 edges per wave-iteration ----------
// MODE 0: plain -> half; MODE 1: LeakyReLU(0.5) -> half; MODE 2: LN+residual -> float
template <int MODE>
__global__ __launch_bounds__(256) void k_spmm_h(const int* __restrict__ starts,
                                                const int2* __restrict__ edges,
                                                const __half2* __restrict__ xh,
                                                __half2* __restrict__ yh,
                                                float* __restrict__ yf,
                                                const float* __restrict__ gamma,
                                                const float* __restrict__ beta,
                                                const float* __restrict__ ego) {
    const int gid  = blockIdx.x * 256 + threadIdx.x;
    const int wid  = gid >> 6;
    const int lane = threadIdx.x & 63;
    if (wid >= NTOT) return;
    const int half_id = lane >> 5;     // 0: even edge of pair, 1: odd edge
    const int c2 = lane & 31;          // half2 column index (cols 2*c2, 2*c2+1)
    const int s  = starts[wid];
    const int e2 = starts[wid + 1];
    float ax = 0.f, ay = 0.f;
    for (int base = s; base < e2; base += 64) {
        const int idx = base + lane;
        int2 ed;
        if (idx < e2) ed = edges[idx]; else { ed.x = 0; ed.y = 0; }
        int nb = e2 - base; if (nb > 64) nb = 64;
        const int npair = (nb + 1) >> 1;
        #pragma unroll 4
        for (int j = 0; j < npair; ++j) {
            const int sel = 2 * j + half_id;
            const int   c = __shfl(ed.x, sel);
            const float v = __int_as_float(__shfl(ed.y, sel));
            const float2 f = __half22float2(xh[c * 32 + c2]);
            ax = fmaf(v, f.x, ax);
            ay = fmaf(v, f.y, ay);
        }
    }
    // combine even/odd-edge partial sums (lanes l and l^32 hold same columns)
    ax += __shfl_xor(ax, 32);
    ay += __shfl_xor(ay, 32);
    if (MODE == 0) {
        if (lane < 32) yh[wid * 32 + c2] = __floats2half2_rn(ax, ay);
    } else if (MODE == 1) {
        if (lane < 32) {
            const float bx = ax > 0.f ? ax : 0.5f * ax;
            const float by = ay > 0.f ? ay : 0.5f * ay;
            yh[wid * 32 + c2] = __floats2half2_rn(bx, by);
        }
    } else {
        float s1 = ax + ay;
        #pragma unroll
        for (int off = 32; off; off >>= 1) s1 += __shfl_xor(s1, off);
        const float mu = s1 * (1.f / 128.f);   // halves duplicate: /(2*64)
        const float dx = ax - mu, dy = ay - mu;
        float q = dx * dx + dy * dy;
        #pragma unroll
        for (int off = 32; off; off >>= 1) q += __shfl_xor(q, off);
        const float rs = rsqrtf(q * (1.f / 128.f) + 1e-5f);
        if (lane < 32) {
            const float2 g2 = ((const float2*)gamma)[c2];
            const float2 b2 = ((const float2*)beta)[c2];
            const float2 eg = ((const float2*)ego)[wid * 32 + c2];
            float2 o;
            o.x = dx * rs * g2.x + b2.x + eg.x;
            o.y = dy * rs * g2.y + b2.y + eg.y;
            ((float2*)yf)[wid * 32 + c2] = o;
        }
    }
}

// ---------- fallback: atomic push (only if ws too small) ----------
__global__ __launch_bounds__(256) void k_push(const int* __restrict__ src_idx,
                                              const int* __restrict__ dst_idx,
                                              const float* __restrict__ vals,
                                              const float* __restrict__ x,
                                              float* __restrict__ y) {
    int gid  = blockIdx.x * 256 + threadIdx.x;
    int e    = gid >> 6;
    int lane = gid & 63;
    if (e >= NE) return;
    atomicAdd(&y[dst_idx[e] * DD + lane], vals[e] * x[src_idx[e] * DD + lane]);
}

__global__ __launch_bounds__(256) void k_leaky(float* __restrict__ x, int n) {
    int i = blockIdx.x * 256 + threadIdx.x;
    if (i < n) { float v = x[i]; x[i] = v > 0.f ? v : 0.5f * v; }
}

__global__ __launch_bounds__(256) void k_ln(const float* __restrict__ z,
                                            const float* __restrict__ gamma,
                                            const float* __restrict__ beta,
                                            const float* __restrict__ ego,
                                            float* __restrict__ out) {
    int gid  = blockIdx.x * 256 + threadIdx.x;
    int wid  = gid >> 6;
    int lane = threadIdx.x & 63;
    if (wid >= NTOT) return;
    float v = z[wid * DD + lane];
    float sum = v;
    #pragma unroll
    for (int off = 32; off; off >>= 1) sum += __shfl_xor(sum, off);
    float mu = sum * (1.f / 64.f);
    float d  = v - mu;
    float vs = d * d;
    #pragma unroll
    for (int off = 32; off; off >>= 1) vs += __shfl_xor(vs, off);
    float rs = rsqrtf(vs * (1.f / 64.f) + 1e-5f);
    out[wid * DD + lane] = d * rs * gamma[lane] + beta[lane] + ego[wid * DD + lane];
}

extern "C" void kernel_launch(void* const* d_in, const int* in_sizes, int n_in,
                              void* d_out, int out_size, void* d_ws, size_t ws_size,
                              hipStream_t stream) {
    const float* ego   = (const float*)d_in[0];
    const float* vals  = (const float*)d_in[1];
    const float* gamma = (const float*)d_in[2];
    const float* beta  = (const float*)d_in[3];
    const int*   rows  = (const int*)d_in[4];
    const int*   cols  = (const int*)d_in[5];
    float* out = (float*)d_out;

    const size_t SEG = (size_t)NE * 8;           // 38,400,000
    const size_t SMETA = 600064;                 // (N+1)*4 padded
    const size_t NEED = 3 * SEG + 2 * SMETA + 6 * 1184 * 4;  // 116,428,544

    if (ws_size >= NEED) {
        char* w = (char*)d_ws;
        int2* csr  = (int2*)w;
        int2* csc  = (int2*)(w + SEG);
        int2* binR = (int2*)(w + 2 * SEG);
        int2* binC = (int2*)d_out;               // d_out (38.4MB) as scratch pre-output
        int* startsR = (int*)(w + 3 * SEG);
        int* startsC = (int*)(w + 3 * SEG + SMETA);
        int* ghR   = (int*)(w + 3 * SEG + 2 * SMETA);
        int* ghC   = ghR + 1184;
        int* baseR = ghC + 1184;
        int* curR  = baseR + 1184;
        int* baseC = curR + 1184;
        int* curC  = baseC + 1184;
        // feature buffers alias dead build scratch
        __half2* B1h  = (__half2*)(w + 2 * SEG);            // binR low 19.2MB
        __half2* B2h  = (__half2*)(w + 2 * SEG + SEG / 2);  // binR high 19.2MB
        __half2* egoh = (__half2*)d_out;                    // binC region, dead after sort

        hipMemsetAsync(ghR, 0, 2 * 1184 * 4, stream);
        k_hist <<<1024, 256, 0, stream>>>(rows, cols, ghR, ghC);
        k_bases<<<1, 1024, 0, stream>>>(ghR, ghC, baseR, curR, baseC, curC, startsR, startsC);
        k_bin  <<<1024, 256, 0, stream>>>(rows, cols, vals, curR, curC, binR, binC);
        k_sort <<<2 * NB, 1024, 0, stream>>>(baseR, binR, csr, startsR, baseC, binC, csc, startsC);
        k_cvt  <<<(NTOT * DD / 2 + 255) / 256, 256, 0, stream>>>((const float2*)ego, egoh, NTOT * DD / 2);

        const int GRID_N = (NTOT * 64) / 256;  // wave per row
        k_spmm_h<0><<<GRID_N, 256, 0, stream>>>(startsC, csc, egoh, B1h, nullptr, nullptr, nullptr, nullptr);
        k_spmm_h<1><<<GRID_N, 256, 0, stream>>>(startsR, csr, B1h, B2h, nullptr, nullptr, nullptr, nullptr);
        k_spmm_h<0><<<GRID_N, 256, 0, stream>>>(startsC, csc, B2h, B1h, nullptr, nullptr, nullptr, nullptr);
        k_spmm_h<1><<<GRID_N, 256, 0, stream>>>(startsR, csr, B1h, B2h, nullptr, nullptr, nullptr, nullptr);
        k_spmm_h<0><<<GRID_N, 256, 0, stream>>>(startsC, csc, B2h, B1h, nullptr, nullptr, nullptr, nullptr);
        k_spmm_h<2><<<GRID_N, 256, 0, stream>>>(startsR, csr, B1h, nullptr, out, gamma, beta, ego);
    } else {
        // atomic-push fallback
        const size_t FEAT_BYTES = (size_t)NTOT * DD * 4;
        float* B1 = (float*)d_ws;
        float* B2 = out;
        const int GRID_P = NE / 4;
        const int GRID_N = (NTOT * DD) / 256;
        const float* e = ego;
        for (int layer = 0; layer < 3; ++layer) {
            hipMemsetAsync(B1, 0, FEAT_BYTES, stream);
            k_push<<<GRID_P, 256, 0, stream>>>(rows, cols, vals, e, B1);
            hipMemsetAsync(B2, 0, FEAT_BYTES, stream);
            k_push<<<GRID_P, 256, 0, stream>>>(cols, rows, vals, B1, B2);
            if (layer < 2) {
                k_leaky<<<GRID_N, 256, 0, stream>>>(B2, NTOT * DD);
                e = B2;
            } else {
                k_ln<<<GRID_N, 256, 0, stream>>>(B2, gamma, beta, ego, out);
            }
        }
    }
}

// Round 3
// 1374.647 us; speedup vs baseline: 2.2969x; 1.7126x over previous
//
#include <hip/hip_runtime.h>
#include <hip/hip_fp16.h>

// HGNN: 3 layers of e = act(A @ (A^T @ e)), N=150000, E=4.8M, D=64.
// Build: atomic-free counting scatter (per-block hist -> scan -> LDS-cursor bin)
// then per-bucket LDS counting sort. SpMM: pull, wave/row, fp16 features,
// 2 edges per wave-iteration, LeakyReLU / LN+residual fused.

#define NTOT 150000
#define NE   4800000
#define DD   64
#define NB   147            // buckets of 1024 rows: ceil(150000/1024)
#define NBLK 512            // build blocks
#define EPB  9375           // edges per build block: ceil(NE/NBLK)

// ---------- phase 1: per-block bucket histogram (no global atomics) ----------
__global__ __launch_bounds__(256) void k_hist(const int* __restrict__ rows,
                                              const int* __restrict__ cols,
                                              int* __restrict__ histR,
                                              int* __restrict__ histC) {
    __shared__ int hR[NB], hC[NB];
    const int tid = threadIdx.x, blk = blockIdx.x;
    for (int i = tid; i < NB; i += 256) { hR[i] = 0; hC[i] = 0; }
    __syncthreads();
    const int e0 = blk * EPB;
    const int e1 = min(NE, e0 + EPB);
    for (int e = e0 + tid; e < e1; e += 256) {
        atomicAdd(&hR[rows[e] >> 10], 1);
        atomicAdd(&hC[cols[e] >> 10], 1);
    }
    __syncthreads();
    for (int i = tid; i < NB; i += 256) {
        histR[i * NBLK + blk] = hR[i];
        histC[i * NBLK + blk] = hC[i];
    }
}

// ---------- phase 2: in-place exclusive scan of [bucket][block] + bucket bounds ----------
__global__ __launch_bounds__(1024) void k_scan2(int* __restrict__ hR, int* __restrict__ hC,
                                                int* __restrict__ bbR, int* __restrict__ bbC) {
    __shared__ int wtot[16], wexcl[16];
    __shared__ int ctot;
    int* a  = blockIdx.x ? hC  : hR;
    int* bb = blockIdx.x ? bbC : bbR;
    const int n = NB * NBLK;
    const int tid  = threadIdx.x;
    const int lane = tid & 63, wv = tid >> 6;
    int carry = 0;
    for (int base = 0; base < n; base += 1024) {
        const int i = base + tid;
        const int v = (i < n) ? a[i] : 0;
        int s = v;
        #pragma unroll
        for (int off = 1; off < 64; off <<= 1) {
            int t = __shfl_up(s, off);
            if (lane >= off) s += t;
        }
        if (lane == 63) wtot[wv] = s;
        __syncthreads();
        if (tid == 0) {
            int run = 0;
            #pragma unroll
            for (int w = 0; w < 16; ++w) { wexcl[w] = run; run += wtot[w]; }
            ctot = run;
        }
        __syncthreads();
        if (i < n) a[i] = carry + wexcl[wv] + (s - v);
        carry += ctot;
        __syncthreads();
    }
    for (int i = tid; i <= NB; i += 1024) bb[i] = (i < NB) ? a[i * NBLK] : NE;
}

// ---------- phase 3: bin edges; cursors live in LDS (block-private ranges) ----------
// payload: x = (local_idx<<18) | other_idx, y = val bits
__global__ __launch_bounds__(256) void k_bin(const int* __restrict__ rows,
                                             const int* __restrict__ cols,
                                             const float* __restrict__ vals,
                                             const int* __restrict__ histR,
                                             const int* __restrict__ histC,
                                             int2* __restrict__ binR,
                                             int2* __restrict__ binC) {
    __shared__ int cR[NB], cC[NB];
    const int tid = threadIdx.x, blk = blockIdx.x;
    for (int i = tid; i < NB; i += 256) {
        cR[i] = histR[i * NBLK + blk];
        cC[i] = histC[i * NBLK + blk];
    }
    __syncthreads();
    const int e0 = blk * EPB;
    const int e1 = min(NE, e0 + EPB);
    for (int e = e0 + tid; e < e1; e += 256) {
        const int r = rows[e], c = cols[e];
        const int vb = __float_as_int(vals[e]);
        int p = atomicAdd(&cR[r >> 10], 1);
        int2 pr; pr.x = ((r & 1023) << 18) | c; pr.y = vb;
        binR[p] = pr;
        int q = atomicAdd(&cC[c >> 10], 1);
        int2 pc; pc.x = ((c & 1023) << 18) | r; pc.y = vb;
        binC[q] = pc;
    }
}

// ---------- phase 4: per-bucket LDS counting sort -> final CSR/CSC + starts ----------
__global__ __launch_bounds__(1024) void k_sort(const int* __restrict__ bbR,
                                               const int2* __restrict__ binR,
                                               int2* __restrict__ csr, int* __restrict__ startsR,
                                               const int* __restrict__ bbC,
                                               const int2* __restrict__ binC,
                                               int2* __restrict__ csc, int* __restrict__ startsC) {
    __shared__ int hist[1024];
    __shared__ int cur[1024];
    __shared__ int wtot[16], wexcl[16];
    const int tid = threadIdx.x;
    const int lane = tid & 63, wv = tid >> 6;
    const int dir = (blockIdx.x >= NB) ? 1 : 0;
    const int b = blockIdx.x - dir * NB;
    const int*  bb     = dir ? bbC     : bbR;
    const int2* bin    = dir ? binC    : binR;
    int2*       out    = dir ? csc     : csr;
    int*        starts = dir ? startsC : startsR;
    const int ebase = bb[b];
    const int eend  = bb[b + 1];
    hist[tid] = 0;
    __syncthreads();
    for (int i = ebase + tid; i < eend; i += 1024)
        atomicAdd(&hist[((unsigned)bin[i].x) >> 18], 1);
    __syncthreads();
    const int v = hist[tid];
    int s = v;
    #pragma unroll
    for (int off = 1; off < 64; off <<= 1) { int t = __shfl_up(s, off); if (lane >= off) s += t; }
    if (lane == 63) wtot[wv] = s;
    __syncthreads();
    if (tid == 0) { int run = 0; for (int w = 0; w < 16; ++w) { wexcl[w] = run; run += wtot[w]; } }
    __syncthreads();
    const int excl = ebase + wexcl[wv] + (s - v);
    const int r0 = b << 10;
    if (r0 + tid < NTOT) starts[r0 + tid] = excl;
    cur[tid] = excl;
    __syncthreads();
    for (int i = ebase + tid; i < eend; i += 1024) {
        const int2 ed = bin[i];
        const int lr = ((unsigned)ed.x) >> 18;
        const int pos = atomicAdd(&cur[lr], 1);
        int2 o; o.x = ed.x & 0x3FFFF; o.y = ed.y;
        out[pos] = o;
    }
    if (blockIdx.x == 0 && tid == 0) { startsR[NTOT] = NE; startsC[NTOT] = NE; }
}

// ---------- ego fp32 -> fp16 ----------
__global__ __launch_bounds__(256) void k_cvt(const float2* __restrict__ x,
                                             __half2* __restrict__ y, int n2) {
    int i = blockIdx.x * 256 + threadIdx.x;
    if (i < n2) y[i] = __float22half2_rn(x[i]);
}

// ---------- pull SpMM, fp16 features, 2 edges per wave-iteration ----------
// MODE 0: plain -> half; MODE 1: LeakyReLU(0.5) -> half; MODE 2: LN+residual -> float
template <int MODE>
__global__ __launch_bounds__(256) void k_spmm_h(const int* __restrict__ starts,
                                                const int2* __restrict__ edges,
                                                const __half2* __restrict__ xh,
                                                __half2* __restrict__ yh,
                                                float* __restrict__ yf,
                                                const float* __restrict__ gamma,
                                                const float* __restrict__ beta,
                                                const float* __restrict__ ego) {
    const int gid  = blockIdx.x * 256 + threadIdx.x;
    const int wid  = gid >> 6;
    const int lane = threadIdx.x & 63;
    if (wid >= NTOT) return;
    const int half_id = lane >> 5;
    const int c2 = lane & 31;
    const int s  = starts[wid];
    const int e2 = starts[wid + 1];
    float ax = 0.f, ay = 0.f;
    for (int base = s; base < e2; base += 64) {
        const int idx = base + lane;
        int2 ed;
        if (idx < e2) ed = edges[idx]; else { ed.x = 0; ed.y = 0; }
        int nb = e2 - base; if (nb > 64) nb = 64;
        const int npair = (nb + 1) >> 1;
        #pragma unroll 4
        for (int j = 0; j < npair; ++j) {
            const int sel = 2 * j + half_id;
            const int   c = __shfl(ed.x, sel);
            const float v = __int_as_float(__shfl(ed.y, sel));
            const float2 f = __half22float2(xh[c * 32 + c2]);
            ax = fmaf(v, f.x, ax);
            ay = fmaf(v, f.y, ay);
        }
    }
    ax += __shfl_xor(ax, 32);
    ay += __shfl_xor(ay, 32);
    if (MODE == 0) {
        if (lane < 32) yh[wid * 32 + c2] = __floats2half2_rn(ax, ay);
    } else if (MODE == 1) {
        if (lane < 32) {
            const float bx = ax > 0.f ? ax : 0.5f * ax;
            const float by = ay > 0.f ? ay : 0.5f * ay;
            yh[wid * 32 + c2] = __floats2half2_rn(bx, by);
        }
    } else {
        float s1 = ax + ay;
        #pragma unroll
        for (int off = 32; off; off >>= 1) s1 += __shfl_xor(s1, off);
        const float mu = s1 * (1.f / 128.f);
        const float dx = ax - mu, dy = ay - mu;
        float q = dx * dx + dy * dy;
        #pragma unroll
        for (int off = 32; off; off >>= 1) q += __shfl_xor(q, off);
        const float rs = rsqrtf(q * (1.f / 128.f) + 1e-5f);
        if (lane < 32) {
            const float2 g2 = ((const float2*)gamma)[c2];
            const float2 b2 = ((const float2*)beta)[c2];
            const float2 eg = ((const float2*)ego)[wid * 32 + c2];
            float2 o;
            o.x = dx * rs * g2.x + b2.x + eg.x;
            o.y = dy * rs * g2.y + b2.y + eg.y;
            ((float2*)yf)[wid * 32 + c2] = o;
        }
    }
}

// ---------- fallback: atomic push (only if ws too small) ----------
__global__ __launch_bounds__(256) void k_push(const int* __restrict__ src_idx,
                                              const int* __restrict__ dst_idx,
                                              const float* __restrict__ vals,
                                              const float* __restrict__ x,
                                              float* __restrict__ y) {
    int gid  = blockIdx.x * 256 + threadIdx.x;
    int e    = gid >> 6;
    int lane = gid & 63;
    if (e >= NE) return;
    atomicAdd(&y[dst_idx[e] * DD + lane], vals[e] * x[src_idx[e] * DD + lane]);
}

__global__ __launch_bounds__(256) void k_leaky(float* __restrict__ x, int n) {
    int i = blockIdx.x * 256 + threadIdx.x;
    if (i < n) { float v = x[i]; x[i] = v > 0.f ? v : 0.5f * v; }
}

__global__ __launch_bounds__(256) void k_ln(const float* __restrict__ z,
                                            const float* __restrict__ gamma,
                                            const float* __restrict__ beta,
                                            const float* __restrict__ ego,
                                            float* __restrict__ out) {
    int gid  = blockIdx.x * 256 + threadIdx.x;
    int wid  = gid >> 6;
    int lane = threadIdx.x & 63;
    if (wid >= NTOT) return;
    float v = z[wid * DD + lane];
    float sum = v;
    #pragma unroll
    for (int off = 32; off; off >>= 1) sum += __shfl_xor(sum, off);
    float mu = sum * (1.f / 64.f);
    float d  = v - mu;
    float vs = d * d;
    #pragma unroll
    for (int off = 32; off; off >>= 1) vs += __shfl_xor(vs, off);
    float rs = rsqrtf(vs * (1.f / 64.f) + 1e-5f);
    out[wid * DD + lane] = d * rs * gamma[lane] + beta[lane] + ego[wid * DD + lane];
}

extern "C" void kernel_launch(void* const* d_in, const int* in_sizes, int n_in,
                              void* d_out, int out_size, void* d_ws, size_t ws_size,
                              hipStream_t stream) {
    const float* ego   = (const float*)d_in[0];
    const float* vals  = (const float*)d_in[1];
    const float* gamma = (const float*)d_in[2];
    const float* beta  = (const float*)d_in[3];
    const int*   rows  = (const int*)d_in[4];
    const int*   cols  = (const int*)d_in[5];
    float* out = (float*)d_out;

    const size_t SEG   = (size_t)NE * 8;          // 38,400,000
    const size_t SMETA = 600064;                  // (N+1)*4 padded
    const size_t NEED  = 3 * SEG + 2 * SMETA + 1280;  // 116,401,408

    if (ws_size >= NEED) {
        char* w = (char*)d_ws;
        int2* csr  = (int2*)w;
        int2* csc  = (int2*)(w + SEG);
        int2* binR = (int2*)(w + 2 * SEG);
        int2* binC = (int2*)d_out;                 // d_out as scratch pre-output
        // hist arrays alias the (not-yet-written) csr/csc regions
        int* histR = (int*)w;                      // NB*NBLK ints = 301,056 B
        int* histC = (int*)(w + SEG);
        int* startsR = (int*)(w + 3 * SEG);
        int* startsC = (int*)(w + 3 * SEG + SMETA);
        int* bbR     = (int*)(w + 3 * SEG + 2 * SMETA);          // NB+1 ints
        int* bbC     = bbR + (NB + 1);
        // feature buffers alias dead build scratch after k_sort
        __half2* B1h  = (__half2*)(w + 2 * SEG);             // binR low 19.2MB
        __half2* B2h  = (__half2*)(w + 2 * SEG + SEG / 2);   // binR high 19.2MB
        __half2* egoh = (__half2*)d_out;                     // binC region

        k_hist <<<NBLK, 256, 0, stream>>>(rows, cols, histR, histC);
        k_scan2<<<2, 1024, 0, stream>>>(histR, histC, bbR, bbC);
        k_bin  <<<NBLK, 256, 0, stream>>>(rows, cols, vals, histR, histC, binR, binC);
        k_sort <<<2 * NB, 1024, 0, stream>>>(bbR, binR, csr, startsR, bbC, binC, csc, startsC);
        k_cvt  <<<(NTOT * DD / 2 + 255) / 256, 256, 0, stream>>>((const float2*)ego, egoh, NTOT * DD / 2);

        const int GRID_N = (NTOT * 64) / 256;  // wave per row
        k_spmm_h<0><<<GRID_N, 256, 0, stream>>>(startsC, csc, egoh, B1h, nullptr, nullptr, nullptr, nullptr);
        k_spmm_h<1><<<GRID_N, 256, 0, stream>>>(startsR, csr, B1h, B2h, nullptr, nullptr, nullptr, nullptr);
        k_spmm_h<0><<<GRID_N, 256, 0, stream>>>(startsC, csc, B2h, B1h, nullptr, nullptr, nullptr, nullptr);
        k_spmm_h<1><<<GRID_N, 256, 0, stream>>>(startsR, csr, B1h, B2h, nullptr, nullptr, nullptr, nullptr);
        k_spmm_h<0><<<GRID_N, 256, 0, stream>>>(startsC, csc, B2h, B1h, nullptr, nullptr, nullptr, nullptr);
        k_spmm_h<2><<<GRID_N, 256, 0, stream>>>(startsR, csr, B1h, nullptr, out, gamma, beta, ego);
    } else {
        // atomic-push fallback
        const size_t FEAT_BYTES = (size_t)NTOT * DD * 4;
        float* B1 = (float*)d_ws;
        float* B2 = out;
        const int GRID_P = NE / 4;
        const int GRID_N = (NTOT * DD) / 256;
        const float* e = ego;
        for (int layer = 0; layer < 3; ++layer) {
            hipMemsetAsync(B1, 0, FEAT_BYTES, stream);
            k_push<<<GRID_P, 256, 0, stream>>>(rows, cols, vals, e, B1);
            hipMemsetAsync(B2, 0, FEAT_BYTES, stream);
            k_push<<<GRID_P, 256, 0, stream>>>(cols, rows, vals, B1, B2);
            if (layer < 2) {
                k_leaky<<<GRID_N, 256, 0, stream>>>(B2, NTOT * DD);
                e = B2;
            } else {
                k_ln<<<GRID_N, 256, 0, stream>>>(B2, gamma, beta, ego, out);
            }
        }
    }
}

// Round 4
// 1283.238 us; speedup vs baseline: 2.4605x; 1.0712x over previous
//
#include <hip/hip_runtime.h>
#include <hip/hip_fp16.h>

// HGNN: 3 layers of e = act(A @ (A^T @ e)), N=150000, E=4.8M, D=64.
// Build: atomic-free counting scatter + per-bucket LDS counting sort.
// SpMM: pull, wave/row, fp16 features in COLUMN-SPLIT layout (two 9.6MB halves
// so each dispatch's random gather set fits L2), 16 edges/wave-iter via
// 4-lane int4 gathers. LeakyReLU / LN+residual fused.

#define NTOT 150000
#define NE   4800000
#define DD   64
#define NB   147            // buckets of 1024 rows
#define NBLK 512            // build blocks
#define EPB  9375           // edges per build block
#define HALF_I4 (NTOT * 4)      // int4 units per feature half-block (64B rows)
#define HALF_H2 (NTOT * 16)     // half2 units per feature half-block

// ---------- phase 1: per-block bucket histogram (no global atomics) ----------
__global__ __launch_bounds__(256) void k_hist(const int* __restrict__ rows,
                                              const int* __restrict__ cols,
                                              int* __restrict__ histR,
                                              int* __restrict__ histC) {
    __shared__ int hR[NB], hC[NB];
    const int tid = threadIdx.x, blk = blockIdx.x;
    for (int i = tid; i < NB; i += 256) { hR[i] = 0; hC[i] = 0; }
    __syncthreads();
    const int e0 = blk * EPB;
    const int e1 = min(NE, e0 + EPB);
    for (int e = e0 + tid; e < e1; e += 256) {
        atomicAdd(&hR[rows[e] >> 10], 1);
        atomicAdd(&hC[cols[e] >> 10], 1);
    }
    __syncthreads();
    for (int i = tid; i < NB; i += 256) {
        histR[i * NBLK + blk] = hR[i];
        histC[i * NBLK + blk] = hC[i];
    }
}

// ---------- phase 2: exclusive scan of [bucket][block] + bucket bounds ----------
__global__ __launch_bounds__(1024) void k_scan2(int* __restrict__ hR, int* __restrict__ hC,
                                                int* __restrict__ bbR, int* __restrict__ bbC) {
    __shared__ int wtot[16], wexcl[16];
    __shared__ int ctot;
    int* a  = blockIdx.x ? hC  : hR;
    int* bb = blockIdx.x ? bbC : bbR;
    const int n = NB * NBLK;
    const int tid  = threadIdx.x;
    const int lane = tid & 63, wv = tid >> 6;
    int carry = 0;
    for (int base = 0; base < n; base += 1024) {
        const int i = base + tid;
        const int v = (i < n) ? a[i] : 0;
        int s = v;
        #pragma unroll
        for (int off = 1; off < 64; off <<= 1) {
            int t = __shfl_up(s, off);
            if (lane >= off) s += t;
        }
        if (lane == 63) wtot[wv] = s;
        __syncthreads();
        if (tid == 0) {
            int run = 0;
            #pragma unroll
            for (int w = 0; w < 16; ++w) { wexcl[w] = run; run += wtot[w]; }
            ctot = run;
        }
        __syncthreads();
        if (i < n) a[i] = carry + wexcl[wv] + (s - v);
        carry += ctot;
        __syncthreads();
    }
    for (int i = tid; i <= NB; i += 1024) bb[i] = (i < NB) ? a[i * NBLK] : NE;
}

// ---------- phase 3: bin edges; cursors in LDS (block-private ranges) ----------
__global__ __launch_bounds__(256) void k_bin(const int* __restrict__ rows,
                                             const int* __restrict__ cols,
                                             const float* __restrict__ vals,
                                             const int* __restrict__ histR,
                                             const int* __restrict__ histC,
                                             int2* __restrict__ binR,
                                             int2* __restrict__ binC) {
    __shared__ int cR[NB], cC[NB];
    const int tid = threadIdx.x, blk = blockIdx.x;
    for (int i = tid; i < NB; i += 256) {
        cR[i] = histR[i * NBLK + blk];
        cC[i] = histC[i * NBLK + blk];
    }
    __syncthreads();
    const int e0 = blk * EPB;
    const int e1 = min(NE, e0 + EPB);
    for (int e = e0 + tid; e < e1; e += 256) {
        const int r = rows[e], c = cols[e];
        const int vb = __float_as_int(vals[e]);
        int p = atomicAdd(&cR[r >> 10], 1);
        int2 pr; pr.x = ((r & 1023) << 18) | c; pr.y = vb;
        binR[p] = pr;
        int q = atomicAdd(&cC[c >> 10], 1);
        int2 pc; pc.x = ((c & 1023) << 18) | r; pc.y = vb;
        binC[q] = pc;
    }
}

// ---------- phase 4: per-bucket LDS counting sort -> CSR/CSC + starts ----------
__global__ __launch_bounds__(1024) void k_sort(const int* __restrict__ bbR,
                                               const int2* __restrict__ binR,
                                               int2* __restrict__ csr, int* __restrict__ startsR,
                                               const int* __restrict__ bbC,
                                               const int2* __restrict__ binC,
                                               int2* __restrict__ csc, int* __restrict__ startsC) {
    __shared__ int hist[1024];
    __shared__ int cur[1024];
    __shared__ int wtot[16], wexcl[16];
    const int tid = threadIdx.x;
    const int lane = tid & 63, wv = tid >> 6;
    const int dir = (blockIdx.x >= NB) ? 1 : 0;
    const int b = blockIdx.x - dir * NB;
    const int*  bb     = dir ? bbC     : bbR;
    const int2* bin    = dir ? binC    : binR;
    int2*       out    = dir ? csc     : csr;
    int*        starts = dir ? startsC : startsR;
    const int ebase = bb[b];
    const int eend  = bb[b + 1];
    hist[tid] = 0;
    __syncthreads();
    for (int i = ebase + tid; i < eend; i += 1024)
        atomicAdd(&hist[((unsigned)bin[i].x) >> 18], 1);
    __syncthreads();
    const int v = hist[tid];
    int s = v;
    #pragma unroll
    for (int off = 1; off < 64; off <<= 1) { int t = __shfl_up(s, off); if (lane >= off) s += t; }
    if (lane == 63) wtot[wv] = s;
    __syncthreads();
    if (tid == 0) { int run = 0; for (int w = 0; w < 16; ++w) { wexcl[w] = run; run += wtot[w]; } }
    __syncthreads();
    const int excl = ebase + wexcl[wv] + (s - v);
    const int r0 = b << 10;
    if (r0 + tid < NTOT) starts[r0 + tid] = excl;
    cur[tid] = excl;
    __syncthreads();
    for (int i = ebase + tid; i < eend; i += 1024) {
        const int2 ed = bin[i];
        const int lr = ((unsigned)ed.x) >> 18;
        const int pos = atomicAdd(&cur[lr], 1);
        int2 o; o.x = ed.x & 0x3FFFF; o.y = ed.y;
        out[pos] = o;
    }
    if (blockIdx.x == 0 && tid == 0) { startsR[NTOT] = NE; startsC[NTOT] = NE; }
}

// ---------- ego fp32 -> fp16 in column-split layout ----------
__global__ __launch_bounds__(256) void k_cvt(const float2* __restrict__ x,
                                             __half2* __restrict__ y) {
    int i = blockIdx.x * 256 + threadIdx.x;   // i over NTOT*32 half2 slots
    const int r = i >> 5, j = i & 31;
    const int half = j >> 4;
    y[half * HALF_H2 + r * 16 + (j & 15)] = __float22half2_rn(x[i]);
}

// ---------- split pull SpMM: one 32-col half, 16 edges/iter, 4 lanes/edge ----------
// MODE 0: plain -> half; MODE 1: LeakyReLU(0.5) -> half
template <int MODE>
__global__ __launch_bounds__(256) void k_spmm_s(const int* __restrict__ starts,
                                                const int2* __restrict__ edges,
                                                const int4* __restrict__ xh,
                                                int4* __restrict__ yh) {
    const int gid  = blockIdx.x * 256 + threadIdx.x;
    const int wid  = gid >> 6;
    const int lane = threadIdx.x & 63;
    if (wid >= NTOT) return;
    const int g = lane >> 2;       // edge group 0..15
    const int l = lane & 3;        // 16B chunk within 64B row (cols 8l..8l+7)
    const int s  = starts[wid];
    const int e2 = starts[wid + 1];
    float acc[8];
    #pragma unroll
    for (int k = 0; k < 8; ++k) acc[k] = 0.f;
    for (int base = s; base < e2; base += 64) {
        const int idx = base + lane;
        int2 ed;
        if (idx < e2) ed = edges[idx]; else { ed.x = 0; ed.y = 0; }
        const int nb = min(e2 - base, 64);
        for (int j = 0; j < nb; j += 16) {
            const int sel = j + g;
            const int   c = __shfl(ed.x, sel);
            const float v = __int_as_float(__shfl(ed.y, sel));
            const int4 q = xh[c * 4 + l];
            const __half2* h2 = (const __half2*)&q;
            #pragma unroll
            for (int k = 0; k < 4; ++k) {
                const float2 f = __half22float2(h2[k]);
                acc[2 * k]     = fmaf(v, f.x, acc[2 * k]);
                acc[2 * k + 1] = fmaf(v, f.y, acc[2 * k + 1]);
            }
        }
    }
    #pragma unroll
    for (int off = 4; off < 64; off <<= 1) {
        #pragma unroll
        for (int k = 0; k < 8; ++k) acc[k] += __shfl_xor(acc[k], off);
    }
    if (l == lane) {  // lane < 4
        __half2 o[4];
        #pragma unroll
        for (int k = 0; k < 4; ++k) {
            float a = acc[2 * k], b = acc[2 * k + 1];
            if (MODE == 1) {
                a = a > 0.f ? a : 0.5f * a;
                b = b > 0.f ? b : 0.5f * b;
            }
            o[k] = __floats2half2_rn(a, b);
        }
        yh[wid * 4 + l] = *(const int4*)o;
    }
}

// ---------- full-row pull SpMM + LayerNorm + residual (final layer) ----------
__global__ __launch_bounds__(256) void k_spmm_f(const int* __restrict__ starts,
                                                const int2* __restrict__ edges,
                                                const int4* __restrict__ xh,   // half0 base
                                                float* __restrict__ out,
                                                const float* __restrict__ gamma,
                                                const float* __restrict__ beta,
                                                const float* __restrict__ ego) {
    const int gid  = blockIdx.x * 256 + threadIdx.x;
    const int wid  = gid >> 6;
    const int lane = threadIdx.x & 63;
    if (wid >= NTOT) return;
    const int g = lane >> 3;       // edge group 0..7
    const int l = lane & 7;        // 16B chunk within 128B row (cols 8l..8l+7)
    const int hoff = (l >> 2) * HALF_I4 + (l & 3);
    const int s  = starts[wid];
    const int e2 = starts[wid + 1];
    float acc[8];
    #pragma unroll
    for (int k = 0; k < 8; ++k) acc[k] = 0.f;
    for (int base = s; base < e2; base += 64) {
        const int idx = base + lane;
        int2 ed;
        if (idx < e2) ed = edges[idx]; else { ed.x = 0; ed.y = 0; }
        const int nb = min(e2 - base, 64);
        for (int j = 0; j < nb; j += 8) {
            const int sel = j + g;
            const int   c = __shfl(ed.x, sel);
            const float v = __int_as_float(__shfl(ed.y, sel));
            const int4 q = xh[c * 4 + hoff];
            const __half2* h2 = (const __half2*)&q;
            #pragma unroll
            for (int k = 0; k < 4; ++k) {
                const float2 f = __half22float2(h2[k]);
                acc[2 * k]     = fmaf(v, f.x, acc[2 * k]);
                acc[2 * k + 1] = fmaf(v, f.y, acc[2 * k + 1]);
            }
        }
    }
    #pragma unroll
    for (int off = 8; off < 64; off <<= 1) {
        #pragma unroll
        for (int k = 0; k < 8; ++k) acc[k] += __shfl_xor(acc[k], off);
    }
    // LayerNorm over 64 cols: acc replicated across the 8 groups; reduce over l.
    float s1 = 0.f;
    #pragma unroll
    for (int k = 0; k < 8; ++k) s1 += acc[k];
    #pragma unroll
    for (int off = 1; off < 8; off <<= 1) s1 += __shfl_xor(s1, off);
    const float mu = s1 * (1.f / 64.f);
    float d[8], q2 = 0.f;
    #pragma unroll
    for (int k = 0; k < 8; ++k) { d[k] = acc[k] - mu; q2 += d[k] * d[k]; }
    #pragma unroll
    for (int off = 1; off < 8; off <<= 1) q2 += __shfl_xor(q2, off);
    const float rs = rsqrtf(q2 * (1.f / 64.f) + 1e-5f);
    if (lane < 8) {
        const float4* g4 = (const float4*)gamma;
        const float4* b4 = (const float4*)beta;
        const float4* e4 = (const float4*)ego + (size_t)wid * 16;
        float4*       o4 = (float4*)out + (size_t)wid * 16;
        #pragma unroll
        for (int half = 0; half < 2; ++half) {
            const float4 gg = g4[2 * l + half];
            const float4 bb = b4[2 * l + half];
            const float4 ee = e4[2 * l + half];
            float4 o;
            o.x = d[4 * half + 0] * rs * gg.x + bb.x + ee.x;
            o.y = d[4 * half + 1] * rs * gg.y + bb.y + ee.y;
            o.z = d[4 * half + 2] * rs * gg.z + bb.z + ee.z;
            o.w = d[4 * half + 3] * rs * gg.w + bb.w + ee.w;
            o4[2 * l + half] = o;
        }
    }
}

// ---------- fallback: atomic push (only if ws too small) ----------
__global__ __launch_bounds__(256) void k_push(const int* __restrict__ src_idx,
                                              const int* __restrict__ dst_idx,
                                              const float* __restrict__ vals,
                                              const float* __restrict__ x,
                                              float* __restrict__ y) {
    int gid  = blockIdx.x * 256 + threadIdx.x;
    int e    = gid >> 6;
    int lane = gid & 63;
    if (e >= NE) return;
    atomicAdd(&y[dst_idx[e] * DD + lane], vals[e] * x[src_idx[e] * DD + lane]);
}

__global__ __launch_bounds__(256) void k_leaky(float* __restrict__ x, int n) {
    int i = blockIdx.x * 256 + threadIdx.x;
    if (i < n) { float v = x[i]; x[i] = v > 0.f ? v : 0.5f * v; }
}

__global__ __launch_bounds__(256) void k_ln(const float* __restrict__ z,
                                            const float* __restrict__ gamma,
                                            const float* __restrict__ beta,
                                            const float* __restrict__ ego,
                                            float* __restrict__ out) {
    int gid  = blockIdx.x * 256 + threadIdx.x;
    int wid  = gid >> 6;
    int lane = threadIdx.x & 63;
    if (wid >= NTOT) return;
    float v = z[wid * DD + lane];
    float sum = v;
    #pragma unroll
    for (int off = 32; off; off >>= 1) sum += __shfl_xor(sum, off);
    float mu = sum * (1.f / 64.f);
    float d  = v - mu;
    float vs = d * d;
    #pragma unroll
    for (int off = 32; off; off >>= 1) vs += __shfl_xor(vs, off);
    float rs = rsqrtf(vs * (1.f / 64.f) + 1e-5f);
    out[wid * DD + lane] = d * rs * gamma[lane] + beta[lane] + ego[wid * DD + lane];
}

extern "C" void kernel_launch(void* const* d_in, const int* in_sizes, int n_in,
                              void* d_out, int out_size, void* d_ws, size_t ws_size,
                              hipStream_t stream) {
    const float* ego   = (const float*)d_in[0];
    const float* vals  = (const float*)d_in[1];
    const float* gamma = (const float*)d_in[2];
    const float* beta  = (const float*)d_in[3];
    const int*   rows  = (const int*)d_in[4];
    const int*   cols  = (const int*)d_in[5];
    float* out = (float*)d_out;

    const size_t SEG   = (size_t)NE * 8;          // 38,400,000
    const size_t SMETA = 600064;
    const size_t NEED  = 3 * SEG + 2 * SMETA + 1280;

    if (ws_size >= NEED) {
        char* w = (char*)d_ws;
        int2* csr  = (int2*)w;
        int2* csc  = (int2*)(w + SEG);
        int2* binR = (int2*)(w + 2 * SEG);
        int2* binC = (int2*)d_out;                 // d_out as scratch pre-output
        int* histR = (int*)w;                      // aliases csr region (dead until k_sort)
        int* histC = (int*)(w + SEG);
        int* startsR = (int*)(w + 3 * SEG);
        int* startsC = (int*)(w + 3 * SEG + SMETA);
        int* bbR     = (int*)(w + 3 * SEG + 2 * SMETA);
        int* bbC     = bbR + (NB + 1);
        // feature buffers (column-split halves) alias dead build scratch
        int4* B1 = (int4*)(w + 2 * SEG);                 // 19.2MB: [half0 9.6][half1 9.6]
        int4* B2 = (int4*)(w + 2 * SEG + SEG / 2);       // 19.2MB
        int4* EG = (int4*)d_out;                          // egoh in d_out (dead binC region)

        k_hist <<<NBLK, 256, 0, stream>>>(rows, cols, histR, histC);
        k_scan2<<<2, 1024, 0, stream>>>(histR, histC, bbR, bbC);
        k_bin  <<<NBLK, 256, 0, stream>>>(rows, cols, vals, histR, histC, binR, binC);
        k_sort <<<2 * NB, 1024, 0, stream>>>(bbR, binR, csr, startsR, bbC, binC, csc, startsC);
        k_cvt  <<<(NTOT * 32) / 256, 256, 0, stream>>>((const float2*)ego, (__half2*)EG);

        const int GRID_N = (NTOT * 64) / 256;  // wave per row
        for (int h = 0; h < 2; ++h)
            k_spmm_s<0><<<GRID_N, 256, 0, stream>>>(startsC, csc, EG + h * HALF_I4, B1 + h * HALF_I4);
        for (int h = 0; h < 2; ++h)
            k_spmm_s<1><<<GRID_N, 256, 0, stream>>>(startsR, csr, B1 + h * HALF_I4, B2 + h * HALF_I4);
        for (int h = 0; h < 2; ++h)
            k_spmm_s<0><<<GRID_N, 256, 0, stream>>>(startsC, csc, B2 + h * HALF_I4, B1 + h * HALF_I4);
        for (int h = 0; h < 2; ++h)
            k_spmm_s<1><<<GRID_N, 256, 0, stream>>>(startsR, csr, B1 + h * HALF_I4, B2 + h * HALF_I4);
        for (int h = 0; h < 2; ++h)
            k_spmm_s<0><<<GRID_N, 256, 0, stream>>>(startsC, csc, B2 + h * HALF_I4, B1 + h * HALF_I4);
        k_spmm_f<<<GRID_N, 256, 0, stream>>>(startsR, csr, B1, out, gamma, beta, ego);
    } else {
        const size_t FEAT_BYTES = (size_t)NTOT * DD * 4;
        float* B1 = (float*)d_ws;
        float* B2 = out;
        const int GRID_P = NE / 4;
        const int GRID_N = (NTOT * DD) / 256;
        const float* e = ego;
        for (int layer = 0; layer < 3; ++layer) {
            hipMemsetAsync(B1, 0, FEAT_BYTES, stream);
            k_push<<<GRID_P, 256, 0, stream>>>(rows, cols, vals, e, B1);
            hipMemsetAsync(B2, 0, FEAT_BYTES, stream);
            k_push<<<GRID_P, 256, 0, stream>>>(cols, rows, vals, B1, B2);
            if (layer < 2) {
                k_leaky<<<GRID_N, 256, 0, stream>>>(B2, NTOT * DD);
                e = B2;
            } else {
                k_ln<<<GRID_N, 256, 0, stream>>>(B2, gamma, beta, ego, out);
            }
        }
    }
}